// Round 9
// baseline (718.767 us; speedup 1.0000x reference)
//
#include <hip/hip_runtime.h>
#include <hip/hip_bf16.h>

#define T_SEQ 2048
#define C_DIM 2048
#define L_DIM 512
#define H_NUM 16
#define S_DIM 128
#define B_SZ  2

typedef __attribute__((ext_vector_type(8))) short bf16x8;
typedef __attribute__((ext_vector_type(4))) float f32x4;
typedef __attribute__((ext_vector_type(4))) short short4v;

__device__ inline short f2bf(float f) {
    union { float f; unsigned u; } x; x.f = f;
    unsigned r = x.u + 0x7fffu + ((x.u >> 16) & 1u);
    return (short)(r >> 16);
}

// ---------------- cast fp32 -> bf16 (vectorized x4) ----------------
__global__ __launch_bounds__(256) void cast_bf16_kernel(const float* __restrict__ in,
                                                        short* __restrict__ out, int n4) {
    int i = blockIdx.x * 256 + threadIdx.x;
    if (i >= n4) return;
    float4 v = ((const float4*)in)[i];
    short4v o;
    o[0] = f2bf(v.x); o[1] = f2bf(v.y); o[2] = f2bf(v.z); o[3] = f2bf(v.w);
    ((short4v*)out)[i] = o;
}

// ------------- transpose + cast: in fp32 [R][C] -> out bf16 [C][R] -------------
__global__ __launch_bounds__(256) void tcast_kernel(const float* __restrict__ in,
                                                    short* __restrict__ out, int R, int C) {
    int c = blockIdx.x * 32 + (threadIdx.x & 31);
    int r = blockIdx.y * 8 + (threadIdx.x >> 5);
    out[(long)c * R + r] = f2bf(in[(long)r * C + c]);
}

// ------------- v [B*T][C] (bf16, viewed [B][T][H][S]) -> vt [B][H][S][T] -------------
__global__ __launch_bounds__(256) void vtrans_kernel(const short* __restrict__ v,
                                                     short* __restrict__ vt) {
    long idx = (long)blockIdx.x * 256 + threadIdx.x;   // over B*H*S*T = 8388608
    int t = (int)(idx & (T_SEQ - 1));
    long r = idx >> 11;
    int s = (int)(r & (S_DIM - 1)); r >>= 7;
    int h = (int)(r & (H_NUM - 1));
    int b = (int)(r >> 4);
    vt[idx] = v[((long)(b * T_SEQ + t)) * C_DIM + h * S_DIM + s];
}

// ------------- generic GEMM: C[M][N] = A[M][K] * Bt[N][K]^T  (bf16 in, fp32 acc) -------------
template<int OUTF32>
__global__ __launch_bounds__(256) void gemm_bt_kernel(
    const short* __restrict__ A, const short* __restrict__ Bt,
    float* __restrict__ Cf, short* __restrict__ Cb,
    int M, int N, int K, int lda, int ldb, int ldc,
    long sAz, long sBz, long sCz)
{
    __shared__ __align__(16) short As[128 * 32];
    __shared__ __align__(16) short Bs[128 * 32];
    int z = blockIdx.z;
    A += (long)z * sAz;
    Bt += (long)z * sBz;
    long coff = (long)z * sCz;
    int tid = threadIdx.x;
    int m0 = blockIdx.y * 128, n0 = blockIdx.x * 128;
    int wave = tid >> 6, l = tid & 63;
    int wm = (wave >> 1) * 64, wn = (wave & 1) * 64;
    int lr = l & 15, lhi = l >> 4;
    f32x4 acc[4][4] = {};

    for (int k0 = 0; k0 < K; k0 += 32) {
        __syncthreads();
        #pragma unroll
        for (int r = 0; r < 2; r++) {
            int e = (r * 256 + tid) * 8;
            int row = e >> 5, col = e & 31;
            __builtin_amdgcn_global_load_lds(
                (const __attribute__((address_space(1))) unsigned int*)(A + (long)(m0 + row) * lda + k0 + col),
                (__attribute__((address_space(3))) unsigned int*)(&As[e]), 16, 0, 0);
            __builtin_amdgcn_global_load_lds(
                (const __attribute__((address_space(1))) unsigned int*)(Bt + (long)(n0 + row) * ldb + k0 + col),
                (__attribute__((address_space(3))) unsigned int*)(&Bs[e]), 16, 0, 0);
        }
        __syncthreads();
        bf16x8 af[4], bfr[4];
        #pragma unroll
        for (int mt = 0; mt < 4; mt++)
            af[mt] = *(const bf16x8*)&As[(wm + mt * 16 + lr) * 32 + lhi * 8];
        #pragma unroll
        for (int nt = 0; nt < 4; nt++)
            bfr[nt] = *(const bf16x8*)&Bs[(wn + nt * 16 + lr) * 32 + lhi * 8];
        #pragma unroll
        for (int mt = 0; mt < 4; mt++)
            #pragma unroll
            for (int nt = 0; nt < 4; nt++)
                acc[mt][nt] = __builtin_amdgcn_mfma_f32_16x16x32_bf16(af[mt], bfr[nt], acc[mt][nt], 0, 0, 0);
    }

    #pragma unroll
    for (int mt = 0; mt < 4; mt++) {
        #pragma unroll
        for (int i = 0; i < 4; i++) {
            int row = m0 + wm + mt * 16 + lhi * 4 + i;
            long base = coff + (long)row * ldc + n0 + wn;
            #pragma unroll
            for (int nt = 0; nt < 4; nt++) {
                float val = acc[mt][nt][i];
                int colo = nt * 16 + lr;
                if (OUTF32) Cf[base + colo] = val;
                else        Cb[base + colo] = f2bf(val);
            }
        }
    }
}

// ------------- flash attention v8: flash7 per-wave structure, 8 waves/block (QBLK=128) -------
// Pure occupancy/amortization change: K staged once per block-chunk serves 8 waves;
// 2 blocks/CU x 8 waves = 16 waves/CU (4/SIMD) to hide the per-chunk serial chain.
__global__ __launch_bounds__(512) void flash8_kernel(
    const short* __restrict__ qlat,  // [H][B][T][L]
    const short* __restrict__ kv,    // [B][T][L]
    const short* __restrict__ vt,    // [B][H][S][T]
    short* __restrict__ y)           // [B][T][C]
{
    __shared__ __align__(16) short Ks[2][32 * 512];   // 2 x 32 KB (double-buffered)
    __shared__ __align__(16) short Ps[8 * 16 * 32];   // 8 KB (1 KB per wave, wave-private)

    int qt = gridDim.x - 1 - blockIdx.x;              // heaviest tiles first
    int t0 = qt * 128;
    int h = blockIdx.y, b = blockIdx.z;
    int tid = threadIdx.x;
    int w = tid >> 6, l = tid & 63, lr = l & 15, lhi = l >> 4;
    int wt0 = t0 + w * 16;
    const short* qb  = qlat + ((long)(h * B_SZ + b)) * T_SEQ * L_DIM;
    const short* kvb = kv + (long)b * T_SEQ * L_DIM;
    const short* vtb = vt + ((long)(b * H_NUM + h)) * S_DIM * T_SEQ;
    char* Pwb = (char*)(Ps + w * 512);

    bf16x8 qf[16];
    #pragma unroll
    for (int ks = 0; ks < 16; ks++)
        qf[ks] = *(const bf16x8*)&qb[(long)(wt0 + lr) * L_DIM + ks * 32 + lhi * 8];

    f32x4 yacc[8] = {};
    float mrun = -__builtin_inff(), lrun = 0.f;
    const float scale = 0.022097086912079608f;  // 1/sqrt(2048)
    int myq = wt0 + lr;

    int nchunk = (t0 >> 5) + 4;

    // prologue: stage chunk 0 into Ks[0] (4 x 16B per thread, 512 threads; src pre-swizzled)
    #pragma unroll
    for (int r = 0; r < 4; r++) {
        int flat = r * 8192 + tid * 16;
        int row = flat >> 10, colb = flat & 1023;
        int src = (row << 10) + (colb ^ ((row & 7) << 4));
        __builtin_amdgcn_global_load_lds(
            (const __attribute__((address_space(1))) unsigned int*)((const char*)kvb + src),
            (__attribute__((address_space(3))) unsigned int*)((char*)Ks[0] + flat), 16, 0, 0);
    }

    for (int c = 0; c < nchunk; c++) {
        int cur = c & 1;
        int s0 = c * 32;
        // barrier A: all waves done reading Ks[cur^1] (prev chunk) -> safe to overwrite
        asm volatile("s_waitcnt lgkmcnt(0)" ::: "memory");
        __builtin_amdgcn_s_barrier();
        if (c + 1 < nchunk) {
            int s0n = s0 + 32;
            #pragma unroll
            for (int r = 0; r < 4; r++) {
                int flat = r * 8192 + tid * 16;
                int row = flat >> 10, colb = flat & 1023;
                int src = ((s0n + row) << 10) + (colb ^ ((row & 7) << 4));
                __builtin_amdgcn_global_load_lds(
                    (const __attribute__((address_space(1))) unsigned int*)((const char*)kvb + src),
                    (__attribute__((address_space(3))) unsigned int*)((char*)Ks[cur ^ 1] + flat), 16, 0, 0);
            }
            asm volatile("s_waitcnt vmcnt(4)" ::: "memory");  // current buf's loads retired
        } else {
            asm volatile("s_waitcnt vmcnt(0)" ::: "memory");
        }
        __builtin_amdgcn_s_barrier();                         // barrier B: Ks[cur] ready

        bool active = (s0 < wt0 + 16);   // wave-uniform
        if (active) {
            // ---- hoist V fragment loads (L2-resident vt), hide latency under softmax ----
            bf16x8 vf[8];
            #pragma unroll
            for (int st = 0; st < 8; st++)
                vf[st] = *(const bf16x8*)&vtb[(long)(st * 16 + lr) * T_SEQ + s0 + lhi * 8];

            // ---- S^T = K·Q^T: swapped mfma args; lane holds 8 k-values of ONE q-col ----
            f32x4 sc[2];
            #pragma unroll
            for (int ct = 0; ct < 2; ct++) {
                int row = ct * 16 + lr;
                int swz = (row & 7) << 4;
                const char* kbase = (const char*)Ks[cur] + (row << 10);
                f32x4 sA = {}, sB = {};
                #pragma unroll
                for (int ks = 0; ks < 8; ks++) {
                    bf16x8 kfA = *(const bf16x8*)(kbase + ((ks * 64 + lhi * 16) ^ swz));
                    bf16x8 kfB = *(const bf16x8*)(kbase + (((ks + 8) * 64 + lhi * 16) ^ swz));
                    sA = __builtin_amdgcn_mfma_f32_16x16x32_bf16(kfA, qf[ks], sA, 0, 0, 0);
                    sB = __builtin_amdgcn_mfma_f32_16x16x32_bf16(kfB, qf[ks + 8], sB, 0, 0, 0);
                }
                sc[ct] = sA + sB;
            }
            // sc[sub][i] = S[k = s0 + sub*16 + lhi*4 + i][q = wt0 + lr]

            // ---- mask + in-lane row max (8 values) + 2 cross-lane levels ----
            float p[2][4], mx = -__builtin_inff();
            #pragma unroll
            for (int sub = 0; sub < 2; sub++)
                #pragma unroll
                for (int i = 0; i < 4; i++) {
                    float a = sc[sub][i] * scale;
                    int kpos = s0 + sub * 16 + lhi * 4 + i;
                    if (kpos > myq) a = -__builtin_inff();
                    p[sub][i] = a;
                    mx = fmaxf(mx, a);
                }
            mx = fmaxf(mx, __shfl_xor(mx, 16));
            mx = fmaxf(mx, __shfl_xor(mx, 32));

            // defer-rescale (exact, THR=0): skip yacc pass when no q-col max grew
            unsigned long long grew = __ballot(mx > mrun);
            if (grew) {
                float mnew = fmaxf(mrun, mx);
                float fac = __expf(mrun - mnew);
                mrun = mnew;
                lrun *= fac;
                float facr[4];
                #pragma unroll
                for (int i = 0; i < 4; i++)
                    facr[i] = __shfl(fac, lhi * 4 + i);    // fac of q-row lhi*4+i
                #pragma unroll
                for (int st = 0; st < 8; st++)
                    #pragma unroll
                    for (int i = 0; i < 4; i++)
                        yacc[st][i] *= facr[i];
            }
            float ls = 0.f;
            #pragma unroll
            for (int sub = 0; sub < 2; sub++)
                #pragma unroll
                for (int i = 0; i < 4; i++) {
                    p[sub][i] = __expf(p[sub][i] - mrun);
                    ls += p[sub][i];
                }
            ls += __shfl_xor(ls, 16);
            ls += __shfl_xor(ls, 32);
            lrun += ls;

            // ---- write P^T rows: lane owns row q=lr, cols k=sub*16+lhi*4+{0..3} ----
            int swz = (lr & 3) << 4;
            char* pb = Pwb + lr * 64;
            #pragma unroll
            for (int sub = 0; sub < 2; sub++) {
                short4v pk;
                #pragma unroll
                for (int i = 0; i < 4; i++) pk[i] = f2bf(p[sub][i]);
                *(short4v*)(pb + ((sub * 32 + lhi * 8) ^ swz)) = pk;
            }
            // in-wave RAW through LDS: drain writes + fence scheduler (rule #18)
            asm volatile("s_waitcnt lgkmcnt(0)" ::: "memory");
            __builtin_amdgcn_sched_barrier(0);
            // ---- PV: P A-frag read (same swizzle), V from regs ----
            bf16x8 pf = *(const bf16x8*)(Pwb + lr * 64 + ((lhi * 16) ^ swz));
            #pragma unroll
            for (int st = 0; st < 8; st++)
                yacc[st] = __builtin_amdgcn_mfma_f32_16x16x32_bf16(pf, vf[st], yacc[st], 0, 0, 0);
        }
    }

    // lrun lives at q=lr lanes; redistribute to yacc's q=lhi*4+i rows
    float lrunr[4];
    #pragma unroll
    for (int i = 0; i < 4; i++)
        lrunr[i] = __shfl(lrun, lhi * 4 + i);
    #pragma unroll
    for (int st = 0; st < 8; st++)
        #pragma unroll
        for (int i = 0; i < 4; i++) {
            int trow = wt0 + lhi * 4 + i;
            float val = yacc[st][i] / lrunr[i];
            y[((long)(b * T_SEQ + trow)) * C_DIM + h * S_DIM + st * 16 + lr] = f2bf(val);
        }
}

extern "C" void kernel_launch(void* const* d_in, const int* in_sizes, int n_in,
                              void* d_out, int out_size, void* d_ws, size_t ws_size,
                              hipStream_t stream) {
    const float* x    = (const float*)d_in[0];
    const float* wdkv = (const float*)d_in[1];
    const float* wuk  = (const float*)d_in[2];
    const float* wuv  = (const float*)d_in[3];
    const float* wq   = (const float*)d_in[4];
    const float* wo   = (const float*)d_in[5];
    float* out = (float*)d_out;

    short* ws = (short*)d_ws;
    size_t off = 0;
    short* xb    = ws + off; off += (size_t)4096 * 2048;   // x bf16 [B*T][C]   (reused as vt)
    short* wqT   = ws + off; off += (size_t)2048 * 2048;   // [C_out][C_in]
    short* wdkvT = ws + off; off += (size_t)512 * 2048;    // [L][C]
    short* wukT  = ws + off; off += (size_t)512 * 2048;    // [L][C]
    short* wuvT  = ws + off; off += (size_t)2048 * 512;    // [C][L]
    short* woT   = ws + off; off += (size_t)2048 * 2048;   // [C][C]
    short* q     = ws + off; off += (size_t)4096 * 2048;   // [B*T][C]         (reused as y)
    short* kvb   = ws + off; off += (size_t)4096 * 512;    // [B*T][L]
    short* vbuf  = ws + off; off += (size_t)4096 * 2048;   // [B*T][C]
    short* qlat  = ws + off; off += (size_t)H_NUM * B_SZ * T_SEQ * L_DIM; // [H][B][T][L]
    short* vtb  = xb;   // vt [B][H][S][T], aliases xb (dead by then)
    short* ybuf = q;    // y  [B][T][C],   aliases q  (dead by then)

    // casts / transposes
    cast_bf16_kernel<<<8192, 256, 0, stream>>>(x, xb, 2097152);
    tcast_kernel<<<dim3(2048 / 32, 2048 / 8), 256, 0, stream>>>(wq, wqT, 2048, 2048);
    tcast_kernel<<<dim3(512 / 32, 2048 / 8), 256, 0, stream>>>(wdkv, wdkvT, 2048, 512);
    tcast_kernel<<<dim3(512 / 32, 2048 / 8), 256, 0, stream>>>(wuk, wukT, 2048, 512);
    tcast_kernel<<<dim3(2048 / 32, 512 / 8), 256, 0, stream>>>(wuv, wuvT, 512, 2048);
    tcast_kernel<<<dim3(2048 / 32, 2048 / 8), 256, 0, stream>>>(wo, woT, 2048, 2048);

    // q = x @ w_q            [4096 x 2048] k=2048
    gemm_bt_kernel<0><<<dim3(16, 32, 1), 256, 0, stream>>>(xb, wqT, nullptr, q,
        4096, 2048, 2048, 2048, 2048, 2048, 0, 0, 0);
    // kv = x @ w_dkv         [4096 x 512] k=2048
    gemm_bt_kernel<0><<<dim3(4, 32, 1), 256, 0, stream>>>(xb, wdkvT, nullptr, kvb,
        4096, 512, 2048, 2048, 2048, 512, 0, 0, 0);
    // qlat[h] = q_h @ w_uk_h [4096 x 512] k=128, batched over 16 heads
    gemm_bt_kernel<0><<<dim3(4, 32, 16), 256, 0, stream>>>(q, wukT, nullptr, qlat,
        4096, 512, 128, 2048, 2048, 512, 128, 128, (long)B_SZ * T_SEQ * L_DIM);
    // v = kv @ w_uv          [4096 x 2048] k=512
    gemm_bt_kernel<0><<<dim3(16, 32, 1), 256, 0, stream>>>(kvb, wuvT, nullptr, vbuf,
        4096, 2048, 512, 512, 512, 2048, 0, 0, 0);
    // v transpose -> [B][H][S][T]
    vtrans_kernel<<<32768, 256, 0, stream>>>(vbuf, vtb);
    // flash attention v8 -> y [B][T][C]
    flash8_kernel<<<dim3(T_SEQ / 128, H_NUM, B_SZ), 512, 0, stream>>>(qlat, kvb, vtb, ybuf);
    // out = y @ w_o          [4096 x 2048] k=2048, fp32 out
    gemm_bt_kernel<1><<<dim3(16, 32, 1), 256, 0, stream>>>(ybuf, woT, out, nullptr,
        4096, 2048, 2048, 2048, 2048, 2048, 0, 0, 0);
}

// Round 10
// 659.947 us; speedup vs baseline: 1.0891x; 1.0891x over previous
//
#include <hip/hip_runtime.h>
#include <hip/hip_bf16.h>

#define T_SEQ 2048
#define C_DIM 2048
#define L_DIM 512
#define H_NUM 16
#define S_DIM 128
#define B_SZ  2

typedef __attribute__((ext_vector_type(8))) short bf16x8;
typedef __attribute__((ext_vector_type(4))) float f32x4;
typedef __attribute__((ext_vector_type(4))) short short4v;

__device__ inline short f2bf(float f) {
    union { float f; unsigned u; } x; x.f = f;
    unsigned r = x.u + 0x7fffu + ((x.u >> 16) & 1u);
    return (short)(r >> 16);
}

// ---------------- cast fp32 -> bf16 (vectorized x4) ----------------
__global__ __launch_bounds__(256) void cast_bf16_kernel(const float* __restrict__ in,
                                                        short* __restrict__ out, int n4) {
    int i = blockIdx.x * 256 + threadIdx.x;
    if (i >= n4) return;
    float4 v = ((const float4*)in)[i];
    short4v o;
    o[0] = f2bf(v.x); o[1] = f2bf(v.y); o[2] = f2bf(v.z); o[3] = f2bf(v.w);
    ((short4v*)out)[i] = o;
}

// ------------- transpose + cast: in fp32 [R][C] -> out bf16 [C][R] -------------
__global__ __launch_bounds__(256) void tcast_kernel(const float* __restrict__ in,
                                                    short* __restrict__ out, int R, int C) {
    int c = blockIdx.x * 32 + (threadIdx.x & 31);
    int r = blockIdx.y * 8 + (threadIdx.x >> 5);
    out[(long)c * R + r] = f2bf(in[(long)r * C + c]);
}

// ------------- v [B*T][C] (bf16, viewed [B][T][H][S]) -> vt [B][H][S][T] -------------
__global__ __launch_bounds__(256) void vtrans_kernel(const short* __restrict__ v,
                                                     short* __restrict__ vt) {
    long idx = (long)blockIdx.x * 256 + threadIdx.x;   // over B*H*S*T = 8388608
    int t = (int)(idx & (T_SEQ - 1));
    long r = idx >> 11;
    int s = (int)(r & (S_DIM - 1)); r >>= 7;
    int h = (int)(r & (H_NUM - 1));
    int b = (int)(r >> 4);
    vt[idx] = v[((long)(b * T_SEQ + t)) * C_DIM + h * S_DIM + s];
}

// ------------- generic GEMM: C[M][N] = A[M][K] * Bt[N][K]^T  (bf16 in, fp32 acc) -------------
template<int OUTF32>
__global__ __launch_bounds__(256) void gemm_bt_kernel(
    const short* __restrict__ A, const short* __restrict__ Bt,
    float* __restrict__ Cf, short* __restrict__ Cb,
    int M, int N, int K, int lda, int ldb, int ldc,
    long sAz, long sBz, long sCz)
{
    __shared__ __align__(16) short As[128 * 32];
    __shared__ __align__(16) short Bs[128 * 32];
    int z = blockIdx.z;
    A += (long)z * sAz;
    Bt += (long)z * sBz;
    long coff = (long)z * sCz;
    int tid = threadIdx.x;
    int m0 = blockIdx.y * 128, n0 = blockIdx.x * 128;
    int wave = tid >> 6, l = tid & 63;
    int wm = (wave >> 1) * 64, wn = (wave & 1) * 64;
    int lr = l & 15, lhi = l >> 4;
    f32x4 acc[4][4] = {};

    for (int k0 = 0; k0 < K; k0 += 32) {
        __syncthreads();
        #pragma unroll
        for (int r = 0; r < 2; r++) {
            int e = (r * 256 + tid) * 8;
            int row = e >> 5, col = e & 31;
            __builtin_amdgcn_global_load_lds(
                (const __attribute__((address_space(1))) unsigned int*)(A + (long)(m0 + row) * lda + k0 + col),
                (__attribute__((address_space(3))) unsigned int*)(&As[e]), 16, 0, 0);
            __builtin_amdgcn_global_load_lds(
                (const __attribute__((address_space(1))) unsigned int*)(Bt + (long)(n0 + row) * ldb + k0 + col),
                (__attribute__((address_space(3))) unsigned int*)(&Bs[e]), 16, 0, 0);
        }
        __syncthreads();
        bf16x8 af[4], bfr[4];
        #pragma unroll
        for (int mt = 0; mt < 4; mt++)
            af[mt] = *(const bf16x8*)&As[(wm + mt * 16 + lr) * 32 + lhi * 8];
        #pragma unroll
        for (int nt = 0; nt < 4; nt++)
            bfr[nt] = *(const bf16x8*)&Bs[(wn + nt * 16 + lr) * 32 + lhi * 8];
        #pragma unroll
        for (int mt = 0; mt < 4; mt++)
            #pragma unroll
            for (int nt = 0; nt < 4; nt++)
                acc[mt][nt] = __builtin_amdgcn_mfma_f32_16x16x32_bf16(af[mt], bfr[nt], acc[mt][nt], 0, 0, 0);
    }

    #pragma unroll
    for (int mt = 0; mt < 4; mt++) {
        #pragma unroll
        for (int i = 0; i < 4; i++) {
            int row = m0 + wm + mt * 16 + lhi * 4 + i;
            long base = coff + (long)row * ldc + n0 + wn;
            #pragma unroll
            for (int nt = 0; nt < 4; nt++) {
                float val = acc[mt][nt][i];
                int colo = nt * 16 + lr;
                if (OUTF32) Cf[base + colo] = val;
                else        Cb[base + colo] = f2bf(val);
            }
        }
    }
}

// ------------- flash attention v9: flash7 body + tile-pairing load balance + 4b K swizzle -----
// Block pr processes q-tiles (31-pr) then (pr): 66 chunks for EVERY block -> 512 uniform blocks,
// 2/CU sustained, no heavy-block tail. K swizzle widened to (row&15)<<4 (perfect 64-lane spread),
// applied to stage-source AND read side (involution pair, rule #21).
__global__ __launch_bounds__(256) void flash9_kernel(
    const short* __restrict__ qlat,  // [H][B][T][L]
    const short* __restrict__ kv,    // [B][T][L]
    const short* __restrict__ vt,    // [B][H][S][T]
    short* __restrict__ y)           // [B][T][C]
{
    __shared__ __align__(16) short Ks[2][32 * 512];   // 2 x 32 KB (double-buffered)
    __shared__ __align__(16) short Ps[4 * 16 * 32];   // 4 KB (1 KB per wave, wave-private)

    int pr = blockIdx.x;                              // 0..15 (pair index)
    int h = blockIdx.y, b = blockIdx.z;
    int tid = threadIdx.x;
    int w = tid >> 6, l = tid & 63, lr = l & 15, lhi = l >> 4;
    const short* qb  = qlat + ((long)(h * B_SZ + b)) * T_SEQ * L_DIM;
    const short* kvb = kv + (long)b * T_SEQ * L_DIM;
    const short* vtb = vt + ((long)(b * H_NUM + h)) * S_DIM * T_SEQ;
    char* Pwb = (char*)(Ps + w * 512);
    const float scale = 0.022097086912079608f;  // 1/sqrt(2048)

    #pragma unroll 1
    for (int sel = 0; sel < 2; sel++) {
        int qt = sel ? pr : (31 - pr);                // heavy tile first
        int t0 = qt * 64;
        int wt0 = t0 + w * 16;
        int myq = wt0 + lr;

        bf16x8 qf[16];
        #pragma unroll
        for (int ks = 0; ks < 16; ks++)
            qf[ks] = *(const bf16x8*)&qb[(long)(wt0 + lr) * L_DIM + ks * 32 + lhi * 8];

        f32x4 yacc[8] = {};
        float mrun = -__builtin_inff(), lrun = 0.f;

        int nchunk = (t0 >> 5) + 2;                   // always even

        // prologue: stage chunk 0 into Ks[0] (8 x 16B per thread; src pre-swizzled, dest linear)
        #pragma unroll
        for (int r = 0; r < 8; r++) {
            int flat = r * 4096 + tid * 16;
            int row = flat >> 10, colb = flat & 1023;
            int src = (row << 10) + (colb ^ ((row & 15) << 4));
            __builtin_amdgcn_global_load_lds(
                (const __attribute__((address_space(1))) unsigned int*)((const char*)kvb + src),
                (__attribute__((address_space(3))) unsigned int*)((char*)Ks[0] + flat), 16, 0, 0);
        }

        for (int c = 0; c < nchunk; c++) {
            int cur = c & 1;
            int s0 = c * 32;
            // barrier A: all waves done reading Ks[cur^1] (prev chunk) -> safe to overwrite
            asm volatile("s_waitcnt lgkmcnt(0)" ::: "memory");
            __builtin_amdgcn_s_barrier();
            if (c + 1 < nchunk) {
                int s0n = s0 + 32;
                #pragma unroll
                for (int r = 0; r < 8; r++) {
                    int flat = r * 4096 + tid * 16;
                    int row = flat >> 10, colb = flat & 1023;
                    int src = ((s0n + row) << 10) + (colb ^ ((row & 15) << 4));
                    __builtin_amdgcn_global_load_lds(
                        (const __attribute__((address_space(1))) unsigned int*)((const char*)kvb + src),
                        (__attribute__((address_space(3))) unsigned int*)((char*)Ks[cur ^ 1] + flat), 16, 0, 0);
                }
                asm volatile("s_waitcnt vmcnt(8)" ::: "memory");  // current buf's 8 loads retired
            } else {
                asm volatile("s_waitcnt vmcnt(0)" ::: "memory");
            }
            __builtin_amdgcn_s_barrier();                         // barrier B: Ks[cur] ready

            bool active = (s0 < wt0 + 16);   // wave-uniform
            if (active) {
                // ---- hoist V fragment loads (L2-resident vt), hide latency under softmax ----
                bf16x8 vf[8];
                #pragma unroll
                for (int st = 0; st < 8; st++)
                    vf[st] = *(const bf16x8*)&vtb[(long)(st * 16 + lr) * T_SEQ + s0 + lhi * 8];

                // ---- S^T = K·Q^T: swapped mfma args; lane holds 8 k-values of ONE q-col ----
                f32x4 sc[2];
                #pragma unroll
                for (int ct = 0; ct < 2; ct++) {
                    int swz = lr << 4;                // (row&15)<<4 with row = ct*16+lr
                    const char* kbase = (const char*)Ks[cur] + ((ct * 16 + lr) << 10);
                    f32x4 sA = {}, sB = {};
                    #pragma unroll
                    for (int ks = 0; ks < 8; ks++) {
                        bf16x8 kfA = *(const bf16x8*)(kbase + ((ks * 64 + lhi * 16) ^ swz));
                        bf16x8 kfB = *(const bf16x8*)(kbase + (((ks + 8) * 64 + lhi * 16) ^ swz));
                        sA = __builtin_amdgcn_mfma_f32_16x16x32_bf16(kfA, qf[ks], sA, 0, 0, 0);
                        sB = __builtin_amdgcn_mfma_f32_16x16x32_bf16(kfB, qf[ks + 8], sB, 0, 0, 0);
                    }
                    sc[ct] = sA + sB;
                }
                // sc[sub][i] = S[k = s0 + sub*16 + lhi*4 + i][q = wt0 + lr]

                // ---- mask + in-lane row max (8 values) + 2 cross-lane levels ----
                float p[2][4], mx = -__builtin_inff();
                #pragma unroll
                for (int sub = 0; sub < 2; sub++)
                    #pragma unroll
                    for (int i = 0; i < 4; i++) {
                        float a = sc[sub][i] * scale;
                        int kpos = s0 + sub * 16 + lhi * 4 + i;
                        if (kpos > myq) a = -__builtin_inff();
                        p[sub][i] = a;
                        mx = fmaxf(mx, a);
                    }
                mx = fmaxf(mx, __shfl_xor(mx, 16));
                mx = fmaxf(mx, __shfl_xor(mx, 32));

                // defer-rescale (exact, THR=0): skip yacc pass when no q-col max grew
                unsigned long long grew = __ballot(mx > mrun);
                if (grew) {
                    float mnew = fmaxf(mrun, mx);
                    float fac = __expf(mrun - mnew);
                    mrun = mnew;
                    lrun *= fac;
                    float facr[4];
                    #pragma unroll
                    for (int i = 0; i < 4; i++)
                        facr[i] = __shfl(fac, lhi * 4 + i);    // fac of q-row lhi*4+i
                    #pragma unroll
                    for (int st = 0; st < 8; st++)
                        #pragma unroll
                        for (int i = 0; i < 4; i++)
                            yacc[st][i] *= facr[i];
                }
                float ls = 0.f;
                #pragma unroll
                for (int sub = 0; sub < 2; sub++)
                    #pragma unroll
                    for (int i = 0; i < 4; i++) {
                        p[sub][i] = __expf(p[sub][i] - mrun);
                        ls += p[sub][i];
                    }
                ls += __shfl_xor(ls, 16);
                ls += __shfl_xor(ls, 32);
                lrun += ls;

                // ---- write P^T rows: lane owns row q=lr, cols k=sub*16+lhi*4+{0..3} ----
                int swz = (lr & 3) << 4;
                char* pb = Pwb + lr * 64;
                #pragma unroll
                for (int sub = 0; sub < 2; sub++) {
                    short4v pk;
                    #pragma unroll
                    for (int i = 0; i < 4; i++) pk[i] = f2bf(p[sub][i]);
                    *(short4v*)(pb + ((sub * 32 + lhi * 8) ^ swz)) = pk;
                }
                // in-wave RAW through LDS: drain writes + fence scheduler (rule #18)
                asm volatile("s_waitcnt lgkmcnt(0)" ::: "memory");
                __builtin_amdgcn_sched_barrier(0);
                // ---- PV: P A-frag read (same swizzle), V from regs ----
                bf16x8 pf = *(const bf16x8*)(Pwb + lr * 64 + ((lhi * 16) ^ swz));
                #pragma unroll
                for (int st = 0; st < 8; st++)
                    yacc[st] = __builtin_amdgcn_mfma_f32_16x16x32_bf16(pf, vf[st], yacc[st], 0, 0, 0);
            }
        }

        // lrun lives at q=lr lanes; redistribute to yacc's q=lhi*4+i rows
        float lrunr[4];
        #pragma unroll
        for (int i = 0; i < 4; i++)
            lrunr[i] = __shfl(lrun, lhi * 4 + i);
        #pragma unroll
        for (int st = 0; st < 8; st++)
            #pragma unroll
            for (int i = 0; i < 4; i++) {
                int trow = wt0 + lhi * 4 + i;
                float val = yacc[st][i] / lrunr[i];
                y[((long)(b * T_SEQ + trow)) * C_DIM + h * S_DIM + st * 16 + lr] = f2bf(val);
            }
    }
}

extern "C" void kernel_launch(void* const* d_in, const int* in_sizes, int n_in,
                              void* d_out, int out_size, void* d_ws, size_t ws_size,
                              hipStream_t stream) {
    const float* x    = (const float*)d_in[0];
    const float* wdkv = (const float*)d_in[1];
    const float* wuk  = (const float*)d_in[2];
    const float* wuv  = (const float*)d_in[3];
    const float* wq   = (const float*)d_in[4];
    const float* wo   = (const float*)d_in[5];
    float* out = (float*)d_out;

    short* ws = (short*)d_ws;
    size_t off = 0;
    short* xb    = ws + off; off += (size_t)4096 * 2048;   // x bf16 [B*T][C]   (reused as vt)
    short* wqT   = ws + off; off += (size_t)2048 * 2048;   // [C_out][C_in]
    short* wdkvT = ws + off; off += (size_t)512 * 2048;    // [L][C]
    short* wukT  = ws + off; off += (size_t)512 * 2048;    // [L][C]
    short* wuvT  = ws + off; off += (size_t)2048 * 512;    // [C][L]
    short* woT   = ws + off; off += (size_t)2048 * 2048;   // [C][C]
    short* q     = ws + off; off += (size_t)4096 * 2048;   // [B*T][C]         (reused as y)
    short* kvb   = ws + off; off += (size_t)4096 * 512;    // [B*T][L]
    short* vbuf  = ws + off; off += (size_t)4096 * 2048;   // [B*T][C]
    short* qlat  = ws + off; off += (size_t)H_NUM * B_SZ * T_SEQ * L_DIM; // [H][B][T][L]
    short* vtb  = xb;   // vt [B][H][S][T], aliases xb (dead by then)
    short* ybuf = q;    // y  [B][T][C],   aliases q  (dead by then)

    // casts / transposes
    cast_bf16_kernel<<<8192, 256, 0, stream>>>(x, xb, 2097152);
    tcast_kernel<<<dim3(2048 / 32, 2048 / 8), 256, 0, stream>>>(wq, wqT, 2048, 2048);
    tcast_kernel<<<dim3(512 / 32, 2048 / 8), 256, 0, stream>>>(wdkv, wdkvT, 2048, 512);
    tcast_kernel<<<dim3(512 / 32, 2048 / 8), 256, 0, stream>>>(wuk, wukT, 2048, 512);
    tcast_kernel<<<dim3(2048 / 32, 512 / 8), 256, 0, stream>>>(wuv, wuvT, 512, 2048);
    tcast_kernel<<<dim3(2048 / 32, 2048 / 8), 256, 0, stream>>>(wo, woT, 2048, 2048);

    // q = x @ w_q            [4096 x 2048] k=2048
    gemm_bt_kernel<0><<<dim3(16, 32, 1), 256, 0, stream>>>(xb, wqT, nullptr, q,
        4096, 2048, 2048, 2048, 2048, 2048, 0, 0, 0);
    // kv = x @ w_dkv         [4096 x 512] k=2048
    gemm_bt_kernel<0><<<dim3(4, 32, 1), 256, 0, stream>>>(xb, wdkvT, nullptr, kvb,
        4096, 512, 2048, 2048, 2048, 512, 0, 0, 0);
    // qlat[h] = q_h @ w_uk_h [4096 x 512] k=128, batched over 16 heads
    gemm_bt_kernel<0><<<dim3(4, 32, 16), 256, 0, stream>>>(q, wukT, nullptr, qlat,
        4096, 512, 128, 2048, 2048, 512, 128, 128, (long)B_SZ * T_SEQ * L_DIM);
    // v = kv @ w_uv          [4096 x 2048] k=512
    gemm_bt_kernel<0><<<dim3(16, 32, 1), 256, 0, stream>>>(kvb, wuvT, nullptr, vbuf,
        4096, 2048, 512, 512, 512, 2048, 0, 0, 0);
    // v transpose -> [B][H][S][T]
    vtrans_kernel<<<32768, 256, 0, stream>>>(vbuf, vtb);
    // flash attention v9 (paired tiles, uniform blocks) -> y [B][T][C]
    flash9_kernel<<<dim3(16, H_NUM, B_SZ), 256, 0, stream>>>(qlat, kvb, vtb, ybuf);
    // out = y @ w_o          [4096 x 2048] k=2048, fp32 out
    gemm_bt_kernel<1><<<dim3(16, 32, 1), 256, 0, stream>>>(ybuf, woT, out, nullptr,
        4096, 2048, 2048, 2048, 2048, 2048, 0, 0, 0);
}

// Round 11
// 652.073 us; speedup vs baseline: 1.1023x; 1.0121x over previous
//
#include <hip/hip_runtime.h>
#include <hip/hip_bf16.h>

#define T_SEQ 2048
#define C_DIM 2048
#define L_DIM 512
#define H_NUM 16
#define S_DIM 128
#define B_SZ  2

typedef __attribute__((ext_vector_type(8))) short bf16x8;
typedef __attribute__((ext_vector_type(4))) float f32x4;
typedef __attribute__((ext_vector_type(4))) short short4v;

__device__ inline short f2bf(float f) {
    union { float f; unsigned u; } x; x.f = f;
    unsigned r = x.u + 0x7fffu + ((x.u >> 16) & 1u);
    return (short)(r >> 16);
}

// ---------------- cast fp32 -> bf16 (vectorized x4) ----------------
__global__ __launch_bounds__(256) void cast_bf16_kernel(const float* __restrict__ in,
                                                        short* __restrict__ out, int n4) {
    int i = blockIdx.x * 256 + threadIdx.x;
    if (i >= n4) return;
    float4 v = ((const float4*)in)[i];
    short4v o;
    o[0] = f2bf(v.x); o[1] = f2bf(v.y); o[2] = f2bf(v.z); o[3] = f2bf(v.w);
    ((short4v*)out)[i] = o;
}

// ------------- transpose + cast: in fp32 [R][C] -> out bf16 [C][R] -------------
__global__ __launch_bounds__(256) void tcast_kernel(const float* __restrict__ in,
                                                    short* __restrict__ out, int R, int C) {
    int c = blockIdx.x * 32 + (threadIdx.x & 31);
    int r = blockIdx.y * 8 + (threadIdx.x >> 5);
    out[(long)c * R + r] = f2bf(in[(long)r * C + c]);
}

// ------------- v [B*T][C] (bf16, viewed [B][T][H][S]) -> vt [B][H][S][T] -------------
__global__ __launch_bounds__(256) void vtrans_kernel(const short* __restrict__ v,
                                                     short* __restrict__ vt) {
    long idx = (long)blockIdx.x * 256 + threadIdx.x;   // over B*H*S*T = 8388608
    int t = (int)(idx & (T_SEQ - 1));
    long r = idx >> 11;
    int s = (int)(r & (S_DIM - 1)); r >>= 7;
    int h = (int)(r & (H_NUM - 1));
    int b = (int)(r >> 4);
    vt[idx] = v[((long)(b * T_SEQ + t)) * C_DIM + h * S_DIM + s];
}

// ------------- generic GEMM: C[M][N] = A[M][K] * Bt[N][K]^T  (bf16 in, fp32 acc) -------------
template<int OUTF32>
__global__ __launch_bounds__(256) void gemm_bt_kernel(
    const short* __restrict__ A, const short* __restrict__ Bt,
    float* __restrict__ Cf, short* __restrict__ Cb,
    int M, int N, int K, int lda, int ldb, int ldc,
    long sAz, long sBz, long sCz)
{
    __shared__ __align__(16) short As[128 * 32];
    __shared__ __align__(16) short Bs[128 * 32];
    int z = blockIdx.z;
    A += (long)z * sAz;
    Bt += (long)z * sBz;
    long coff = (long)z * sCz;
    int tid = threadIdx.x;
    int m0 = blockIdx.y * 128, n0 = blockIdx.x * 128;
    int wave = tid >> 6, l = tid & 63;
    int wm = (wave >> 1) * 64, wn = (wave & 1) * 64;
    int lr = l & 15, lhi = l >> 4;
    f32x4 acc[4][4] = {};

    for (int k0 = 0; k0 < K; k0 += 32) {
        __syncthreads();
        #pragma unroll
        for (int r = 0; r < 2; r++) {
            int e = (r * 256 + tid) * 8;
            int row = e >> 5, col = e & 31;
            __builtin_amdgcn_global_load_lds(
                (const __attribute__((address_space(1))) unsigned int*)(A + (long)(m0 + row) * lda + k0 + col),
                (__attribute__((address_space(3))) unsigned int*)(&As[e]), 16, 0, 0);
            __builtin_amdgcn_global_load_lds(
                (const __attribute__((address_space(1))) unsigned int*)(Bt + (long)(n0 + row) * ldb + k0 + col),
                (__attribute__((address_space(3))) unsigned int*)(&Bs[e]), 16, 0, 0);
        }
        __syncthreads();
        bf16x8 af[4], bfr[4];
        #pragma unroll
        for (int mt = 0; mt < 4; mt++)
            af[mt] = *(const bf16x8*)&As[(wm + mt * 16 + lr) * 32 + lhi * 8];
        #pragma unroll
        for (int nt = 0; nt < 4; nt++)
            bfr[nt] = *(const bf16x8*)&Bs[(wn + nt * 16 + lr) * 32 + lhi * 8];
        #pragma unroll
        for (int mt = 0; mt < 4; mt++)
            #pragma unroll
            for (int nt = 0; nt < 4; nt++)
                acc[mt][nt] = __builtin_amdgcn_mfma_f32_16x16x32_bf16(af[mt], bfr[nt], acc[mt][nt], 0, 0, 0);
    }

    #pragma unroll
    for (int mt = 0; mt < 4; mt++) {
        #pragma unroll
        for (int i = 0; i < 4; i++) {
            int row = m0 + wm + mt * 16 + lhi * 4 + i;
            long base = coff + (long)row * ldc + n0 + wn;
            #pragma unroll
            for (int nt = 0; nt < 4; nt++) {
                float val = acc[mt][nt][i];
                int colo = nt * 16 + lr;
                if (OUTF32) Cf[base + colo] = val;
                else        Cb[base + colo] = f2bf(val);
            }
        }
    }
}

// ------------- flash attention v10: flash9 body, 36KB LDS (single K buffer) for 3 blocks/CU ---
// Residency model: usable LDS/CU ~140KB; 68KB kernels got 2 blocks/CU, this gets 3.
// Sync per chunk: B1 = vmcnt(0)+barrier (stage landed) -> compute reads (V first, then QK)
// -> B2 = lgkmcnt(0)+barrier (all K reads done) -> stage c+1 (latency hides under softmax+PV
// and the 2 other resident blocks). PV's implicit V-wait = vmcnt(8), not a drain (FIFO).
__global__ __launch_bounds__(256) void flash10_kernel(
    const short* __restrict__ qlat,  // [H][B][T][L]
    const short* __restrict__ kv,    // [B][T][L]
    const short* __restrict__ vt,    // [B][H][S][T]
    short* __restrict__ y)           // [B][T][C]
{
    __shared__ __align__(16) short Ks[32 * 512];      // 32 KB, single buffer
    __shared__ __align__(16) short Ps[4 * 16 * 32];   // 4 KB (1 KB per wave, wave-private)

    int pr = blockIdx.x;                              // 0..15 (pair index)
    int h = blockIdx.y, b = blockIdx.z;
    int tid = threadIdx.x;
    int w = tid >> 6, l = tid & 63, lr = l & 15, lhi = l >> 4;
    const short* qb  = qlat + ((long)(h * B_SZ + b)) * T_SEQ * L_DIM;
    const short* kvb = kv + (long)b * T_SEQ * L_DIM;
    const short* vtb = vt + ((long)(b * H_NUM + h)) * S_DIM * T_SEQ;
    char* Pwb = (char*)(Ps + w * 512);
    const float scale = 0.022097086912079608f;  // 1/sqrt(2048)

    // stage chunk [32 rows] at kv row S0ROW into Ks (src pre-swizzled, dest linear; rule #21)
#define STAGE_K(S0ROW) do { \
        _Pragma("unroll") \
        for (int r = 0; r < 8; r++) { \
            int flat = r * 4096 + tid * 16; \
            int row = flat >> 10, colb = flat & 1023; \
            int src = (((S0ROW) + row) << 10) + (colb ^ ((row & 15) << 4)); \
            __builtin_amdgcn_global_load_lds( \
                (const __attribute__((address_space(1))) unsigned int*)((const char*)kvb + src), \
                (__attribute__((address_space(3))) unsigned int*)((char*)Ks + flat), 16, 0, 0); \
        } \
    } while (0)

    #pragma unroll 1
    for (int sel = 0; sel < 2; sel++) {
        int qt = sel ? pr : (31 - pr);                // heavy tile first
        int t0 = qt * 64;
        int wt0 = t0 + w * 16;
        int myq = wt0 + lr;

        bf16x8 qf[16];
        #pragma unroll
        for (int ks = 0; ks < 16; ks++)
            qf[ks] = *(const bf16x8*)&qb[(long)(wt0 + lr) * L_DIM + ks * 32 + lhi * 8];

        f32x4 yacc[8] = {};
        float mrun = -__builtin_inff(), lrun = 0.f;

        int nchunk = (t0 >> 5) + 2;

        if (sel == 0) STAGE_K(0);   // sel=1 prologue staged at end of sel=0 epilogue below

        for (int c = 0; c < nchunk; c++) {
            int s0 = c * 32;
            // B1: this wave's stage loads landed; barrier -> all waves' loads landed
            asm volatile("s_waitcnt vmcnt(0)" ::: "memory");
            __builtin_amdgcn_s_barrier();

            bool active = (s0 < wt0 + 16);   // wave-uniform
            bf16x8 vf[8];
            f32x4 sc[2];
            if (active) {
                // ---- V fragment loads FIRST (oldest in VMEM queue; L2-resident vt) ----
                #pragma unroll
                for (int st = 0; st < 8; st++)
                    vf[st] = *(const bf16x8*)&vtb[(long)(st * 16 + lr) * T_SEQ + s0 + lhi * 8];

                // ---- S^T = K·Q^T: swapped mfma args; lane holds 8 k-values of ONE q-col ----
                #pragma unroll
                for (int ct = 0; ct < 2; ct++) {
                    int swz = lr << 4;                // (row&15)<<4 with row = ct*16+lr
                    const char* kbase = (const char*)Ks + ((ct * 16 + lr) << 10);
                    f32x4 sA = {}, sB = {};
                    #pragma unroll
                    for (int ks = 0; ks < 8; ks++) {
                        bf16x8 kfA = *(const bf16x8*)(kbase + ((ks * 64 + lhi * 16) ^ swz));
                        bf16x8 kfB = *(const bf16x8*)(kbase + (((ks + 8) * 64 + lhi * 16) ^ swz));
                        sA = __builtin_amdgcn_mfma_f32_16x16x32_bf16(kfA, qf[ks], sA, 0, 0, 0);
                        sB = __builtin_amdgcn_mfma_f32_16x16x32_bf16(kfB, qf[ks + 8], sB, 0, 0, 0);
                    }
                    sc[ct] = sA + sB;
                }
            }
            // B2: this wave's K reads retired; barrier -> ALL waves done reading Ks
            asm volatile("s_waitcnt lgkmcnt(0)" ::: "memory");
            __builtin_amdgcn_s_barrier();
            // stage next chunk NOW: latency hides under softmax+PV + 2 other blocks
            if (c + 1 < nchunk) STAGE_K(s0 + 32);

            if (active) {
                // sc[sub][i] = S[k = s0 + sub*16 + lhi*4 + i][q = wt0 + lr]
                // ---- mask + in-lane row max (8 values) + 2 cross-lane levels ----
                float p[2][4], mx = -__builtin_inff();
                #pragma unroll
                for (int sub = 0; sub < 2; sub++)
                    #pragma unroll
                    for (int i = 0; i < 4; i++) {
                        float a = sc[sub][i] * scale;
                        int kpos = s0 + sub * 16 + lhi * 4 + i;
                        if (kpos > myq) a = -__builtin_inff();
                        p[sub][i] = a;
                        mx = fmaxf(mx, a);
                    }
                mx = fmaxf(mx, __shfl_xor(mx, 16));
                mx = fmaxf(mx, __shfl_xor(mx, 32));

                // defer-rescale (exact, THR=0): skip yacc pass when no q-col max grew
                unsigned long long grew = __ballot(mx > mrun);
                if (grew) {
                    float mnew = fmaxf(mrun, mx);
                    float fac = __expf(mrun - mnew);
                    mrun = mnew;
                    lrun *= fac;
                    float facr[4];
                    #pragma unroll
                    for (int i = 0; i < 4; i++)
                        facr[i] = __shfl(fac, lhi * 4 + i);    // fac of q-row lhi*4+i
                    #pragma unroll
                    for (int st = 0; st < 8; st++)
                        #pragma unroll
                        for (int i = 0; i < 4; i++)
                            yacc[st][i] *= facr[i];
                }
                float ls = 0.f;
                #pragma unroll
                for (int sub = 0; sub < 2; sub++)
                    #pragma unroll
                    for (int i = 0; i < 4; i++) {
                        p[sub][i] = __expf(p[sub][i] - mrun);
                        ls += p[sub][i];
                    }
                ls += __shfl_xor(ls, 16);
                ls += __shfl_xor(ls, 32);
                lrun += ls;

                // ---- write P^T rows: lane owns row q=lr, cols k=sub*16+lhi*4+{0..3} ----
                int swz = (lr & 3) << 4;
                char* pb = Pwb + lr * 64;
                #pragma unroll
                for (int sub = 0; sub < 2; sub++) {
                    short4v pk;
                    #pragma unroll
                    for (int i = 0; i < 4; i++) pk[i] = f2bf(p[sub][i]);
                    *(short4v*)(pb + ((sub * 32 + lhi * 8) ^ swz)) = pk;
                }
                // in-wave RAW through LDS: drain writes + fence scheduler (rule #18)
                asm volatile("s_waitcnt lgkmcnt(0)" ::: "memory");
                __builtin_amdgcn_sched_barrier(0);
                // ---- PV: P A-frag read (same swizzle), V from regs (implicit vmcnt(8)) ----
                bf16x8 pf = *(const bf16x8*)(Pwb + lr * 64 + ((lhi * 16) ^ swz));
                #pragma unroll
                for (int st = 0; st < 8; st++)
                    yacc[st] = __builtin_amdgcn_mfma_f32_16x16x32_bf16(pf, vf[st], yacc[st], 0, 0, 0);
            }
        }

        // stage the next sweep's first chunk (all Ks reads of this sweep retired at last B2)
        if (sel == 0) STAGE_K(0);

        // lrun lives at q=lr lanes; redistribute to yacc's q=lhi*4+i rows
        float lrunr[4];
        #pragma unroll
        for (int i = 0; i < 4; i++)
            lrunr[i] = __shfl(lrun, lhi * 4 + i);
        #pragma unroll
        for (int st = 0; st < 8; st++)
            #pragma unroll
            for (int i = 0; i < 4; i++) {
                int trow = wt0 + lhi * 4 + i;
                float val = yacc[st][i] / lrunr[i];
                y[((long)(b * T_SEQ + trow)) * C_DIM + h * S_DIM + st * 16 + lr] = f2bf(val);
            }
    }
#undef STAGE_K
}

extern "C" void kernel_launch(void* const* d_in, const int* in_sizes, int n_in,
                              void* d_out, int out_size, void* d_ws, size_t ws_size,
                              hipStream_t stream) {
    const float* x    = (const float*)d_in[0];
    const float* wdkv = (const float*)d_in[1];
    const float* wuk  = (const float*)d_in[2];
    const float* wuv  = (const float*)d_in[3];
    const float* wq   = (const float*)d_in[4];
    const float* wo   = (const float*)d_in[5];
    float* out = (float*)d_out;

    short* ws = (short*)d_ws;
    size_t off = 0;
    short* xb    = ws + off; off += (size_t)4096 * 2048;   // x bf16 [B*T][C]   (reused as vt)
    short* wqT   = ws + off; off += (size_t)2048 * 2048;   // [C_out][C_in]
    short* wdkvT = ws + off; off += (size_t)512 * 2048;    // [L][C]
    short* wukT  = ws + off; off += (size_t)512 * 2048;    // [L][C]
    short* wuvT  = ws + off; off += (size_t)2048 * 512;    // [C][L]
    short* woT   = ws + off; off += (size_t)2048 * 2048;   // [C][C]
    short* q     = ws + off; off += (size_t)4096 * 2048;   // [B*T][C]         (reused as y)
    short* kvb   = ws + off; off += (size_t)4096 * 512;    // [B*T][L]
    short* vbuf  = ws + off; off += (size_t)4096 * 2048;   // [B*T][C]
    short* qlat  = ws + off; off += (size_t)H_NUM * B_SZ * T_SEQ * L_DIM; // [H][B][T][L]
    short* vtb  = xb;   // vt [B][H][S][T], aliases xb (dead by then)
    short* ybuf = q;    // y  [B][T][C],   aliases q  (dead by then)

    // casts / transposes
    cast_bf16_kernel<<<8192, 256, 0, stream>>>(x, xb, 2097152);
    tcast_kernel<<<dim3(2048 / 32, 2048 / 8), 256, 0, stream>>>(wq, wqT, 2048, 2048);
    tcast_kernel<<<dim3(512 / 32, 2048 / 8), 256, 0, stream>>>(wdkv, wdkvT, 2048, 512);
    tcast_kernel<<<dim3(512 / 32, 2048 / 8), 256, 0, stream>>>(wuk, wukT, 2048, 512);
    tcast_kernel<<<dim3(2048 / 32, 512 / 8), 256, 0, stream>>>(wuv, wuvT, 512, 2048);
    tcast_kernel<<<dim3(2048 / 32, 2048 / 8), 256, 0, stream>>>(wo, woT, 2048, 2048);

    // q = x @ w_q            [4096 x 2048] k=2048
    gemm_bt_kernel<0><<<dim3(16, 32, 1), 256, 0, stream>>>(xb, wqT, nullptr, q,
        4096, 2048, 2048, 2048, 2048, 2048, 0, 0, 0);
    // kv = x @ w_dkv         [4096 x 512] k=2048
    gemm_bt_kernel<0><<<dim3(4, 32, 1), 256, 0, stream>>>(xb, wdkvT, nullptr, kvb,
        4096, 512, 2048, 2048, 2048, 512, 0, 0, 0);
    // qlat[h] = q_h @ w_uk_h [4096 x 512] k=128, batched over 16 heads
    gemm_bt_kernel<0><<<dim3(4, 32, 16), 256, 0, stream>>>(q, wukT, nullptr, qlat,
        4096, 512, 128, 2048, 2048, 512, 128, 128, (long)B_SZ * T_SEQ * L_DIM);
    // v = kv @ w_uv          [4096 x 2048] k=512
    gemm_bt_kernel<0><<<dim3(16, 32, 1), 256, 0, stream>>>(kvb, wuvT, nullptr, vbuf,
        4096, 2048, 512, 512, 512, 2048, 0, 0, 0);
    // v transpose -> [B][H][S][T]
    vtrans_kernel<<<32768, 256, 0, stream>>>(vbuf, vtb);
    // flash attention v10 (paired tiles, 36KB LDS, 3 blocks/CU) -> y [B][T][C]
    flash10_kernel<<<dim3(16, H_NUM, B_SZ), 256, 0, stream>>>(qlat, kvb, vtb, ybuf);
    // out = y @ w_o          [4096 x 2048] k=2048, fp32 out
    gemm_bt_kernel<1><<<dim3(16, 32, 1), 256, 0, stream>>>(ybuf, woT, out, nullptr,
        4096, 2048, 2048, 2048, 2048, 2048, 0, 0, 0);
}